// Round 19
// baseline (1045.241 us; speedup 1.0000x reference)
//
#include <hip/hip_runtime.h>
#include <math.h>

// BlockwiseEarlyExitMamba: B=128, L=64, EXIT_POS=32 -> only t<32 matter.
// v20 = v19 (passing, 343us) UNCHANGED + one ablation dispatch (abl_kernel):
// v19's body with all GEMM k-loops removed (accs = 0; all LDS dumps,
// barriers, conv, scan, LN run faithfully), 4 internal reps so it lands in
// the rocprof top-5. Purpose: ground-truth split of GEMM vs non-GEMM time
// after 19 rounds of unattributed ~250us. Real output untouched.
#define BATCH 128

using bf16x8 = __attribute__((ext_vector_type(8))) short;
using f32x4  = __attribute__((ext_vector_type(4))) float;
typedef unsigned short ushort_t;
typedef unsigned int   uint_t;

__device__ __forceinline__ float silu_f(float x) { return x / (1.f + __expf(-x)); }

__device__ __forceinline__ ushort_t bf16_rne(float f) {
  unsigned int u = __float_as_uint(f);
  u += 0x7FFFu + ((u >> 16) & 1u);
  return (ushort_t)(u >> 16);
}
__device__ __forceinline__ float bf16_to_f(ushort_t h) {
  return __uint_as_float(((unsigned int)h) << 16);
}
__device__ __forceinline__ void bf16_split(float f, ushort_t& hi, ushort_t& lo) {
  hi = bf16_rne(f);
  lo = bf16_rne(f - bf16_to_f(hi));
}

// single-A x split-W: a*(wh+wl) (2 MFMAs)
__device__ __forceinline__ f32x4 mfma2(bf16x8 a, bf16x8 wh, bf16x8 wl, f32x4 acc) {
  acc = __builtin_amdgcn_mfma_f32_16x16x32_bf16(a, wh, acc, 0, 0, 0);
  acc = __builtin_amdgcn_mfma_f32_16x16x32_bf16(a, wl, acc, 0, 0, 0);
  return acc;
}

// 2-tile (32 out cols) GEMM, straight loop (register-light).
template<int KSTEPS, int AP, int WP>
__device__ __forceinline__ void gemm2(
    const ushort_t* sA, const ushort_t* wh, const ushort_t* wl, f32x4 acc[2][2]) {
  for (int ks = 0; ks < KSTEPS; ++ks) {
    int k0 = ks*32;
    bf16x8 a0 = *(const bf16x8*)(sA + k0);
    bf16x8 a1 = *(const bf16x8*)(sA + 16*AP + k0);
    bf16x8 w0 = *(const bf16x8*)(wh + k0);
    bf16x8 l0 = *(const bf16x8*)(wl + k0);
    bf16x8 w1 = *(const bf16x8*)(wh + 16*WP + k0);
    bf16x8 l1 = *(const bf16x8*)(wl + 16*WP + k0);
    acc[0][0] = mfma2(a0, w0, l0, acc[0][0]);
    acc[1][0] = mfma2(a1, w0, l0, acc[1][0]);
    acc[0][1] = mfma2(a0, w1, l1, acc[0][1]);
    acc[1][1] = mfma2(a1, w1, l1, acc[1][1]);
  }
}

// 1-tile (16 out cols) variant.
template<int KSTEPS, int AP, int WP>
__device__ __forceinline__ void gemm1(
    const ushort_t* sA, const ushort_t* wh, const ushort_t* wl, f32x4 acc[2]) {
  for (int ks = 0; ks < KSTEPS; ++ks) {
    int k0 = ks*32;
    bf16x8 a0 = *(const bf16x8*)(sA + k0);
    bf16x8 a1 = *(const bf16x8*)(sA + 16*AP + k0);
    bf16x8 w0 = *(const bf16x8*)(wh + k0);
    bf16x8 l0 = *(const bf16x8*)(wl + k0);
    acc[0] = mfma2(a0, w0, l0, acc[0]);
    acc[1] = mfma2(a1, w0, l0, acc[1]);
  }
}

// ---------------- merged weight prep: fp32 -> hi/lo bf16 ----------------
#define NIP (4*1024*256)
#define NOP (4*256*512)
#define NXP (4*64*512)
#define NFW (256*160)
#define NPREP (NIP+NOP+NXP+NFW)   // 1744896 = 6816*256
__global__ __launch_bounds__(256) void prep_w(
    const float* __restrict__ ipw, const float* __restrict__ opw,
    const float* __restrict__ xpw, const float* __restrict__ fw,
    ushort_t* __restrict__ ih, ushort_t* __restrict__ il,
    ushort_t* __restrict__ oh, ushort_t* __restrict__ ol,
    ushort_t* __restrict__ xh, ushort_t* __restrict__ xl,
    ushort_t* __restrict__ fh, ushort_t* __restrict__ fl) {
  int i = blockIdx.x*256 + threadIdx.x;
  float v; ushort_t h, l;
  if (i < NIP) {
    v = ipw[i]; bf16_split(v, h, l); ih[i] = h; il[i] = l;
  } else if (i < NIP+NOP) {
    int j = i - NIP;
    v = opw[j]; bf16_split(v, h, l); oh[j] = h; ol[j] = l;
  } else if (i < NIP+NOP+NXP) {
    int j = i - (NIP+NOP);
    int lay = j >> 15;
    int r = (j >> 9) & 63, c = j & 511;
    v = (r < 48) ? xpw[(size_t)lay*48*512 + r*512 + c] : 0.f;
    bf16_split(v, h, l); xh[j] = h; xl[j] = l;
  } else {
    int j = i - (NIP+NOP+NXP);
    int r = j / 160, c = j - r*160;
    v = (c < 136) ? fw[r*136 + c] : 0.f;
    bf16_split(v, h, l); fh[j] = h; fl[j] = l;
  }
}

// ---------------- LDS layout (bytes) ----------------
// A: sF32 f32 [32][260]             33280
// B: union { sFh us [32][264] | sT2 f32 [32][260] | sDbc f32 4x[32][64] | sHid }
// C: sU  us [32][520]               33280
// D: sZb us [32][520]               33280
#define OFF_A 0
#define OFF_B 33280
#define OFF_C 66560
#define OFF_D 99840
#define SMEM_TOTAL 133120

__device__ __forceinline__ void ln_block(
    const float* sIn, const float* resid, const float* addv,
    const float* __restrict__ g, const float* __restrict__ bb,
    float* sF32o, ushort_t* sFho, int tid) {
  int row = tid >> 5, sub = tid & 31;
  float v[8];
  float s = 0.f;
  #pragma unroll
  for (int i = 0; i < 8; ++i) {
    int c = sub + 32*i;
    float t = sIn[row*260 + c];
    if (resid) t += resid[row*260 + c];
    if (addv)  t += addv[c];
    v[i] = t; s += t;
  }
  s += __shfl_xor(s, 1); s += __shfl_xor(s, 2); s += __shfl_xor(s, 4);
  s += __shfl_xor(s, 8); s += __shfl_xor(s, 16);
  float mu = s * (1.f/256.f);
  float s2 = 0.f;
  #pragma unroll
  for (int i = 0; i < 8; ++i) { float dv = v[i]-mu; s2 += dv*dv; }
  s2 += __shfl_xor(s2, 1); s2 += __shfl_xor(s2, 2); s2 += __shfl_xor(s2, 4);
  s2 += __shfl_xor(s2, 8); s2 += __shfl_xor(s2, 16);
  float rs = rsqrtf(s2*(1.f/256.f) + 1e-5f);
  __syncthreads();
  #pragma unroll
  for (int i = 0; i < 8; ++i) {
    int c = sub + 32*i;
    float o = (v[i]-mu)*rs*g[c] + bb[c];
    sF32o[row*260 + c] = o;
    sFho[row*264 + c] = bf16_rne(o);
  }
}

// ---------------- shared body: GEMMS=1 real kernel, GEMMS=0 ablation ----------
template<int GEMMS>
__device__ __forceinline__ void mega_body(
    const float* x,
    const float* ep, const float* ef, const float* ed,
    const float* plw, const float* plb, const float* piw, const float* pib,
    const ushort_t* fw_h, const ushort_t* fw_l, const float* fb,
    const float* tng, const float* tnb,
    const ushort_t* ipw_h, const ushort_t* ipw_l,
    const float* cw, const float* cb,
    const ushort_t* xpw_h, const ushort_t* xpw_l,
    const float* dpw, const float* dpb, const float* alog, const float* dsk,
    const ushort_t* opw_h, const ushort_t* opw_l,
    const float* lng, const float* lnb,
    const float* w1, const float* b1, const float* w2, const float* b2,
    float* out, char* sm, int b) {
  float*    sF32 = (float*)(sm + OFF_A);
  ushort_t* sFh  = (ushort_t*)(sm + OFF_B);
  float*    sT2  = (float*)(sm + OFF_B);
  float*    sDbc = (float*)(sm + OFF_B);
  float*    sHid = (float*)(sm + OFF_B);
  ushort_t* sU   = (ushort_t*)(sm + OFF_C);
  ushort_t* catH = (ushort_t*)(sm + OFF_C);
  ushort_t* sZb  = (ushort_t*)(sm + OFF_D);

  const int tid  = threadIdx.x;
  const int wave = tid >> 6, lane = tid & 63;
  const int lm   = lane & 15, lq = lane >> 4;

  // ================= tokenizer =================
  {
    int r = tid >> 5, cl = tid & 31;
    const float* xr = x + ((size_t)b*64 + r)*5;
    float x0 = xr[0], x1 = xr[1], x2 = xr[2], x3 = xr[3], x4 = xr[4];
    int proto = min(max((int)x0, 0), 255);
    int flags = min(max((int)x2, 0), 63);
    int direc = min(max((int)x4, 0), 1);
    #pragma unroll
    for (int j = 0; j < 6; ++j) {
      int c = cl + 32*j;
      if (c < 168) {
        float v;
        if (c < 32)       v = ep[proto*32 + c];
        else if (c < 64)  v = x1*plw[c-32] + plb[c-32];
        else if (c < 96)  v = ef[flags*32 + (c-64)];
        else if (c < 128) v = x3*piw[c-96] + pib[c-96];
        else if (c < 136) v = ed[direc*8 + (c-128)];
        else              v = 0.f;
        catH[r*168 + c] = bf16_rne(v);
      }
    }
  }
  __syncthreads();
  // fusion GEMM
  {
    f32x4 acc[2] = {(f32x4){0.f,0.f,0.f,0.f}, (f32x4){0.f,0.f,0.f,0.f}};
    int nb = wave*16;
    if (GEMMS)
      gemm1<5, 168, 160>(catH + lm*168 + lq*8,
                         fw_h + (size_t)(nb+lm)*160 + lq*8,
                         fw_l + (size_t)(nb+lm)*160 + lq*8, acc);
    #pragma unroll
    for (int mi = 0; mi < 2; ++mi)
      #pragma unroll
      for (int r2 = 0; r2 < 4; ++r2)
        sT2[(mi*16 + lq*4 + r2)*260 + nb + lm] = acc[mi][r2];
  }
  __syncthreads();
  ln_block(sT2, nullptr, fb, tng, tnb, sF32, sFh, tid);
  __syncthreads();

  // ================= 4 mamba layers =================
  #pragma unroll 1
  for (int l = 0; l < 4; ++l) {
    const ushort_t* iph = ipw_h + (size_t)l*1024*256;
    const ushort_t* ipl2= ipw_l + (size_t)l*1024*256;
    const ushort_t* xph = xpw_h + (size_t)l*64*512;
    const ushort_t* xpl = xpw_l + (size_t)l*64*512;
    const ushort_t* oph = opw_h + (size_t)l*256*512;
    const ushort_t* opl = opw_l + (size_t)l*256*512;
    const ushort_t* sA = sFh + lm*264 + lq*8;

    // ---- Z GEMM -> silu(z) bf16 into sZb ----
    {
      f32x4 acc[2][2];
      #pragma unroll
      for (int mi = 0; mi < 2; ++mi)
        #pragma unroll
        for (int nt = 0; nt < 2; ++nt) acc[mi][nt] = (f32x4){0.f,0.f,0.f,0.f};
      int row0 = 512 + wave*32;
      if (GEMMS)
        gemm2<8, 264, 256>(sA,
                           iph + (size_t)(row0+lm)*256 + lq*8,
                           ipl2 + (size_t)(row0+lm)*256 + lq*8, acc);
      int nb = wave*32;
      #pragma unroll
      for (int mi = 0; mi < 2; ++mi)
        #pragma unroll
        for (int nt = 0; nt < 2; ++nt)
          #pragma unroll
          for (int r2 = 0; r2 < 4; ++r2) {
            int t = mi*16 + lq*4 + r2;
            int n = nb + nt*16 + lm;
            sZb[t*520 + n] = bf16_rne(silu_f(acc[mi][nt][r2]));
          }
    }

    // ---- U GEMM -> u_pre bf16 into sU ----
    {
      f32x4 acc[2][2];
      #pragma unroll
      for (int mi = 0; mi < 2; ++mi)
        #pragma unroll
        for (int nt = 0; nt < 2; ++nt) acc[mi][nt] = (f32x4){0.f,0.f,0.f,0.f};
      int row0 = wave*32;
      if (GEMMS)
        gemm2<8, 264, 256>(sA,
                           iph + (size_t)(row0+lm)*256 + lq*8,
                           ipl2 + (size_t)(row0+lm)*256 + lq*8, acc);
      int nb = wave*32;
      #pragma unroll
      for (int mi = 0; mi < 2; ++mi)
        #pragma unroll
        for (int nt = 0; nt < 2; ++nt)
          #pragma unroll
          for (int r2 = 0; r2 < 4; ++r2) {
            int t = mi*16 + lq*4 + r2;
            int n = nb + nt*16 + lm;
            sU[t*520 + n] = bf16_rne(acc[mi][nt][r2]);
          }
    }
    __syncthreads();

    // ---- conv + silu ----
    {
      int c = tid & 511, hv = tid >> 9;
      int h16 = hv*16;
      float xw[19];
      #pragma unroll
      for (int j = 0; j < 19; ++j) {
        int gt = h16 + j - 3;
        xw[j] = (gt >= 0) ? bf16_to_f(sU[gt*520 + c]) : 0.f;
      }
      __syncthreads();
      const float* cwl = cw + (size_t)l*2048 + (size_t)c*4;
      float w0 = cwl[0], w1c = cwl[1], w2c = cwl[2], w3 = cwl[3];
      float bias = cb[l*512 + c];
      #pragma unroll
      for (int tt = 0; tt < 16; ++tt) {
        float a = bias + w0*xw[tt] + w1c*xw[tt+1] + w2c*xw[tt+2] + w3*xw[tt+3];
        sU[(h16+tt)*520 + c] = bf16_rne(silu_f(a));
      }
    }
    __syncthreads();

    // ---- xproj -> sDbc partials + reduce ----
    {
      int wg = wave & 3, kh = wave >> 2;
      f32x4 acx[2] = {(f32x4){0.f,0.f,0.f,0.f}, (f32x4){0.f,0.f,0.f,0.f}};
      if (GEMMS)
        gemm1<4, 520, 512>(sU + lm*520 + kh*128 + lq*8,
                           xph + (size_t)(wg*16+lm)*512 + kh*128 + lq*8,
                           xpl + (size_t)(wg*16+lm)*512 + kh*128 + lq*8, acx);
      float* dst = sDbc + kh*2048;
      #pragma unroll
      for (int mi = 0; mi < 2; ++mi)
        #pragma unroll
        for (int r2 = 0; r2 < 4; ++r2)
          dst[(mi*16 + lq*4 + r2)*64 + wg*16 + lm] = acx[mi][r2];
    }
    __syncthreads();
    {
      int i0 = tid*2;
      #pragma unroll
      for (int j = 0; j < 2; ++j) {
        int i = i0 + j;
        sDbc[i] += sDbc[2048+i] + sDbc[4096+i] + sDbc[6144+i];
      }
    }
    __syncthreads();

    // ---- dtproj + scan + gate ----
    {
      int c = tid >> 1, p = tid & 1;
      const float* dpwl = dpw + (size_t)l*8192 + (size_t)c*16 + p*8;
      float wv[8];
      #pragma unroll
      for (int j = 0; j < 8; ++j) wv[j] = dpwl[j];
      const float* al2 = alog + (size_t)l*8192 + (size_t)c*16 + p*8;
      float cc[8], hst[8];
      #pragma unroll
      for (int j = 0; j < 8; ++j) {
        cc[j] = -__expf(al2[j]) * 1.44269504f;
        hst[j] = 0.f;
      }
      float bias = dpb[l*512 + c], dskv = dsk[l*512 + c];
      #pragma unroll 2
      for (int t = 0; t < 32; ++t) {
        const float* rowp = sDbc + t*64;
        float raw = 0.f;
        #pragma unroll
        for (int j = 0; j < 8; ++j) raw += wv[j]*rowp[p*8 + j];
        raw += __shfl_xor(raw, 1);
        raw += bias;
        float dtv = (raw > 20.f) ? raw : __logf(1.f + __expf(raw));
        int ui = t*520 + c;
        float uv = bf16_to_f(sU[ui]);
        float du = dtv * uv;
        float yv = 0.f;
        #pragma unroll
        for (int j = 0; j < 8; ++j) {
          int n = p*8 + j;
          float en = exp2f(dtv * cc[j]);
          hst[j] = en*hst[j] + du*rowp[16 + n];
          yv += hst[j]*rowp[32 + n];
        }
        yv += __shfl_xor(yv, 1);
        if (p == 0) {
          float g = (yv + uv*dskv) * bf16_to_f(sZb[ui]);
          sU[ui] = bf16_rne(g);
        }
      }
    }
    __syncthreads();

    // ---- out_proj ----
    {
      f32x4 ao[2] = {(f32x4){0.f,0.f,0.f,0.f}, (f32x4){0.f,0.f,0.f,0.f}};
      int nb = wave*16;
      if (GEMMS)
        gemm1<16, 520, 512>(sU + lm*520 + lq*8,
                            oph + (size_t)(nb+lm)*512 + lq*8,
                            opl + (size_t)(nb+lm)*512 + lq*8, ao);
      #pragma unroll
      for (int mi = 0; mi < 2; ++mi)
        #pragma unroll
        for (int r2 = 0; r2 < 4; ++r2)
          sT2[(mi*16 + lq*4 + r2)*260 + nb + lm] = ao[mi][r2];
    }
    __syncthreads();
    ln_block(sT2, sF32, nullptr, lng, lnb, sF32, sFh, tid);
    __syncthreads();
  }

  // ================= classifier (token 31) =================
  {
    int o = tid >> 3, q = tid & 7;
    const float* fr = sF32 + 31*260 + q*32;
    const float* wr = w1 + (size_t)o*256 + q*32;
    float s = 0.f;
    #pragma unroll 8
    for (int k = 0; k < 32; ++k) s += wr[k]*fr[k];
    s += __shfl_xor(s, 1); s += __shfl_xor(s, 2); s += __shfl_xor(s, 4);
    if (q == 0) sHid[o] = fmaxf(s + b1[o], 0.f);
    __syncthreads();
    if (tid < 2) {
      float oo = b2[tid];
      #pragma unroll 8
      for (int k = 0; k < 128; ++k) oo += w2[tid*128 + k]*sHid[k];
      out[b*2 + tid] = oo;
    }
  }
}

// ---------------- real kernel ----------
__global__ __launch_bounds__(1024, 4) void mega_kernel(
    const float* __restrict__ x,
    const float* __restrict__ ep, const float* __restrict__ ef, const float* __restrict__ ed,
    const float* __restrict__ plw, const float* __restrict__ plb,
    const float* __restrict__ piw, const float* __restrict__ pib,
    const ushort_t* __restrict__ fw_h, const ushort_t* __restrict__ fw_l,
    const float* __restrict__ fb,
    const float* __restrict__ tng, const float* __restrict__ tnb,
    const ushort_t* __restrict__ ipw_h, const ushort_t* __restrict__ ipw_l,
    const float* __restrict__ cw, const float* __restrict__ cb,
    const ushort_t* __restrict__ xpw_h, const ushort_t* __restrict__ xpw_l,
    const float* __restrict__ dpw, const float* __restrict__ dpb,
    const float* __restrict__ alog, const float* __restrict__ dsk,
    const ushort_t* __restrict__ opw_h, const ushort_t* __restrict__ opw_l,
    const float* __restrict__ lng, const float* __restrict__ lnb,
    const float* __restrict__ w1, const float* __restrict__ b1,
    const float* __restrict__ w2, const float* __restrict__ b2,
    float* __restrict__ out) {
  extern __shared__ __align__(16) char sm[];
  mega_body<1>(x, ep, ef, ed, plw, plb, piw, pib, fw_h, fw_l, fb, tng, tnb,
               ipw_h, ipw_l, cw, cb, xpw_h, xpw_l, dpw, dpb, alog, dsk,
               opw_h, opw_l, lng, lnb, w1, b1, w2, b2, out, sm, blockIdx.x);
}

// ---------------- ablation kernel: no GEMMs, 4 reps, writes scratch ----------
__global__ __launch_bounds__(1024, 4) void abl_kernel(
    const float* __restrict__ x,
    const float* __restrict__ ep, const float* __restrict__ ef, const float* __restrict__ ed,
    const float* __restrict__ plw, const float* __restrict__ plb,
    const float* __restrict__ piw, const float* __restrict__ pib,
    const ushort_t* __restrict__ fw_h, const ushort_t* __restrict__ fw_l,
    const float* __restrict__ fb,
    const float* __restrict__ tng, const float* __restrict__ tnb,
    const ushort_t* __restrict__ ipw_h, const ushort_t* __restrict__ ipw_l,
    const float* __restrict__ cw, const float* __restrict__ cb,
    const ushort_t* __restrict__ xpw_h, const ushort_t* __restrict__ xpw_l,
    const float* __restrict__ dpw, const float* __restrict__ dpb,
    const float* __restrict__ alog, const float* __restrict__ dsk,
    const ushort_t* __restrict__ opw_h, const ushort_t* __restrict__ opw_l,
    const float* __restrict__ lng, const float* __restrict__ lnb,
    const float* __restrict__ w1, const float* __restrict__ b1,
    const float* __restrict__ w2, const float* __restrict__ b2,
    float* __restrict__ scratch) {
  extern __shared__ __align__(16) char sm[];
  #pragma unroll 1
  for (int rep = 0; rep < 4; ++rep) {
    mega_body<0>(x, ep, ef, ed, plw, plb, piw, pib, fw_h, fw_l, fb, tng, tnb,
                 ipw_h, ipw_l, cw, cb, xpw_h, xpw_l, dpw, dpb, alog, dsk,
                 opw_h, opw_l, lng, lnb, w1, b1, w2, b2, scratch, sm, blockIdx.x);
    __syncthreads();
  }
}

// ---------------- launch ----------------
extern "C" void kernel_launch(void* const* d_in, const int* in_sizes, int n_in,
                              void* d_out, int out_size, void* d_ws, size_t ws_size,
                              hipStream_t stream) {
  const float* x    = (const float*)d_in[0];
  const float* ep   = (const float*)d_in[1];
  const float* ef   = (const float*)d_in[2];
  const float* ed   = (const float*)d_in[3];
  const float* plw  = (const float*)d_in[4];
  const float* plb  = (const float*)d_in[5];
  const float* piw  = (const float*)d_in[6];
  const float* pib  = (const float*)d_in[7];
  const float* fw   = (const float*)d_in[8];
  const float* fb   = (const float*)d_in[9];
  const float* tng  = (const float*)d_in[10];
  const float* tnb  = (const float*)d_in[11];
  const float* ipw  = (const float*)d_in[12];
  const float* cw   = (const float*)d_in[13];
  const float* cb   = (const float*)d_in[14];
  const float* xpw  = (const float*)d_in[15];
  const float* dpw  = (const float*)d_in[16];
  const float* dpb  = (const float*)d_in[17];
  const float* alog = (const float*)d_in[18];
  const float* dsk  = (const float*)d_in[19];
  const float* opw  = (const float*)d_in[20];
  const float* lng  = (const float*)d_in[21];
  const float* lnb  = (const float*)d_in[22];
  const float* w1   = (const float*)d_in[23];
  const float* b1   = (const float*)d_in[24];
  const float* w2   = (const float*)d_in[25];
  const float* b2   = (const float*)d_in[26];

  ushort_t* ipw_h = (ushort_t*)d_ws;
  ushort_t* ipw_l = ipw_h + (size_t)NIP;
  ushort_t* opw_h = ipw_l + (size_t)NIP;
  ushort_t* opw_l = opw_h + (size_t)NOP;
  ushort_t* xpw_h = opw_l + (size_t)NOP;
  ushort_t* xpw_l = xpw_h + (size_t)NXP;
  ushort_t* fw_h  = xpw_l + (size_t)NXP;
  ushort_t* fw_l  = fw_h  + (size_t)NFW;
  float*    scr   = (float*)(fw_l + (size_t)NFW);   // ablation logits scratch

  static int smem_set = 0;
  if (!smem_set) {
    hipFuncSetAttribute(reinterpret_cast<const void*>(mega_kernel),
                        hipFuncAttributeMaxDynamicSharedMemorySize, SMEM_TOTAL);
    hipFuncSetAttribute(reinterpret_cast<const void*>(abl_kernel),
                        hipFuncAttributeMaxDynamicSharedMemorySize, SMEM_TOTAL);
    smem_set = 1;
  }

  prep_w<<<NPREP/256, 256, 0, stream>>>(ipw, opw, xpw, fw,
      ipw_h, ipw_l, opw_h, opw_l, xpw_h, xpw_l, fw_h, fw_l);

  mega_kernel<<<BATCH, 1024, SMEM_TOTAL, stream>>>(
      x, ep, ef, ed, plw, plb, piw, pib,
      fw_h, fw_l, fb, tng, tnb,
      ipw_h, ipw_l, cw, cb, xpw_h, xpw_l,
      dpw, dpb, alog, dsk, opw_h, opw_l,
      lng, lnb, w1, b1, w2, b2, (float*)d_out);

  abl_kernel<<<BATCH, 1024, SMEM_TOTAL, stream>>>(
      x, ep, ef, ed, plw, plb, piw, pib,
      fw_h, fw_l, fb, tng, tnb,
      ipw_h, ipw_l, cw, cb, xpw_h, xpw_l,
      dpw, dpb, alog, dsk, opw_h, opw_l,
      lng, lnb, w1, b1, w2, b2, scr);
}

// Round 20
// 443.208 us; speedup vs baseline: 2.3584x; 2.3584x over previous
//
#include <hip/hip_runtime.h>
#include <math.h>

// BlockwiseEarlyExitMamba: B=128, L=64, EXIT_POS=32 -> only t<32 matter.
// v22 = v19 (passing, 343us) with ONE change: the scan's dbc-row reads are
// vectorized (6x f32x4 per t-step instead of 24 scalar f32 LDS reads) --
// a regression introduced in the pair-split port (v13 had vector reads).
// Accumulation order preserved -> bit-identical numerics to v19.
// Round-20 ablation: non-GEMM = 154us (VALU ~84%/busy CU, ~80% scan),
// GEMM-added = 189us. This attacks the scan's LDS/VALU instruction count.
#define BATCH 128

using bf16x8 = __attribute__((ext_vector_type(8))) short;
using f32x4  = __attribute__((ext_vector_type(4))) float;
typedef unsigned short ushort_t;
typedef unsigned int   uint_t;

__device__ __forceinline__ float silu_f(float x) { return x / (1.f + __expf(-x)); }

__device__ __forceinline__ ushort_t bf16_rne(float f) {
  unsigned int u = __float_as_uint(f);
  u += 0x7FFFu + ((u >> 16) & 1u);
  return (ushort_t)(u >> 16);
}
__device__ __forceinline__ float bf16_to_f(ushort_t h) {
  return __uint_as_float(((unsigned int)h) << 16);
}
__device__ __forceinline__ void bf16_split(float f, ushort_t& hi, ushort_t& lo) {
  hi = bf16_rne(f);
  lo = bf16_rne(f - bf16_to_f(hi));
}

// single-A x split-W: a*(wh+wl) (2 MFMAs)
__device__ __forceinline__ f32x4 mfma2(bf16x8 a, bf16x8 wh, bf16x8 wl, f32x4 acc) {
  acc = __builtin_amdgcn_mfma_f32_16x16x32_bf16(a, wh, acc, 0, 0, 0);
  acc = __builtin_amdgcn_mfma_f32_16x16x32_bf16(a, wl, acc, 0, 0, 0);
  return acc;
}

// 2-tile (32 out cols) GEMM, straight loop (register-light).
template<int KSTEPS, int AP, int WP>
__device__ __forceinline__ void gemm2(
    const ushort_t* sA, const ushort_t* wh, const ushort_t* wl, f32x4 acc[2][2]) {
  for (int ks = 0; ks < KSTEPS; ++ks) {
    int k0 = ks*32;
    bf16x8 a0 = *(const bf16x8*)(sA + k0);
    bf16x8 a1 = *(const bf16x8*)(sA + 16*AP + k0);
    bf16x8 w0 = *(const bf16x8*)(wh + k0);
    bf16x8 l0 = *(const bf16x8*)(wl + k0);
    bf16x8 w1 = *(const bf16x8*)(wh + 16*WP + k0);
    bf16x8 l1 = *(const bf16x8*)(wl + 16*WP + k0);
    acc[0][0] = mfma2(a0, w0, l0, acc[0][0]);
    acc[1][0] = mfma2(a1, w0, l0, acc[1][0]);
    acc[0][1] = mfma2(a0, w1, l1, acc[0][1]);
    acc[1][1] = mfma2(a1, w1, l1, acc[1][1]);
  }
}

// 1-tile (16 out cols) variant.
template<int KSTEPS, int AP, int WP>
__device__ __forceinline__ void gemm1(
    const ushort_t* sA, const ushort_t* wh, const ushort_t* wl, f32x4 acc[2]) {
  for (int ks = 0; ks < KSTEPS; ++ks) {
    int k0 = ks*32;
    bf16x8 a0 = *(const bf16x8*)(sA + k0);
    bf16x8 a1 = *(const bf16x8*)(sA + 16*AP + k0);
    bf16x8 w0 = *(const bf16x8*)(wh + k0);
    bf16x8 l0 = *(const bf16x8*)(wl + k0);
    acc[0] = mfma2(a0, w0, l0, acc[0]);
    acc[1] = mfma2(a1, w0, l0, acc[1]);
  }
}

// ---------------- merged weight prep: fp32 -> hi/lo bf16 ----------------
#define NIP (4*1024*256)
#define NOP (4*256*512)
#define NXP (4*64*512)
#define NFW (256*160)
#define NPREP (NIP+NOP+NXP+NFW)   // 1744896 = 6816*256
__global__ __launch_bounds__(256) void prep_w(
    const float* __restrict__ ipw, const float* __restrict__ opw,
    const float* __restrict__ xpw, const float* __restrict__ fw,
    ushort_t* __restrict__ ih, ushort_t* __restrict__ il,
    ushort_t* __restrict__ oh, ushort_t* __restrict__ ol,
    ushort_t* __restrict__ xh, ushort_t* __restrict__ xl,
    ushort_t* __restrict__ fh, ushort_t* __restrict__ fl) {
  int i = blockIdx.x*256 + threadIdx.x;
  float v; ushort_t h, l;
  if (i < NIP) {
    v = ipw[i]; bf16_split(v, h, l); ih[i] = h; il[i] = l;
  } else if (i < NIP+NOP) {
    int j = i - NIP;
    v = opw[j]; bf16_split(v, h, l); oh[j] = h; ol[j] = l;
  } else if (i < NIP+NOP+NXP) {
    int j = i - (NIP+NOP);
    int lay = j >> 15;
    int r = (j >> 9) & 63, c = j & 511;
    v = (r < 48) ? xpw[(size_t)lay*48*512 + r*512 + c] : 0.f;
    bf16_split(v, h, l); xh[j] = h; xl[j] = l;
  } else {
    int j = i - (NIP+NOP+NXP);
    int r = j / 160, c = j - r*160;
    v = (c < 136) ? fw[r*136 + c] : 0.f;
    bf16_split(v, h, l); fh[j] = h; fl[j] = l;
  }
}

// ---------------- LDS layout (bytes) ----------------
// A: sF32 f32 [32][260]             33280  (residual feat, persistent)
// B: union { sFh us [32][264] (feat bf16) | sT2 f32 [32][260] |
//            sDbc f32 4x[32][64] | sHid f32[128] }   33280
// C: sU  us [32][520]               33280  (u_pre -> u -> y; aliased catH)
// D: sZb us [32][520]               33280  (silu(z) bf16)
#define OFF_A 0
#define OFF_B 33280
#define OFF_C 66560
#define OFF_D 99840
#define SMEM_TOTAL 133120

// LN of [32][256]; 32 threads/row (1024 threads). Reads sIn (+resid +addv);
// internal barrier; writes sF32o + bf16 sFho.
__device__ __forceinline__ void ln_block(
    const float* sIn, const float* resid, const float* addv,
    const float* __restrict__ g, const float* __restrict__ bb,
    float* sF32o, ushort_t* sFho, int tid) {
  int row = tid >> 5, sub = tid & 31;
  float v[8];
  float s = 0.f;
  #pragma unroll
  for (int i = 0; i < 8; ++i) {
    int c = sub + 32*i;
    float t = sIn[row*260 + c];
    if (resid) t += resid[row*260 + c];
    if (addv)  t += addv[c];
    v[i] = t; s += t;
  }
  s += __shfl_xor(s, 1); s += __shfl_xor(s, 2); s += __shfl_xor(s, 4);
  s += __shfl_xor(s, 8); s += __shfl_xor(s, 16);
  float mu = s * (1.f/256.f);
  float s2 = 0.f;
  #pragma unroll
  for (int i = 0; i < 8; ++i) { float dv = v[i]-mu; s2 += dv*dv; }
  s2 += __shfl_xor(s2, 1); s2 += __shfl_xor(s2, 2); s2 += __shfl_xor(s2, 4);
  s2 += __shfl_xor(s2, 8); s2 += __shfl_xor(s2, 16);
  float rs = rsqrtf(s2*(1.f/256.f) + 1e-5f);
  __syncthreads();              // sIn aliases sFho: read-before, write-after
  #pragma unroll
  for (int i = 0; i < 8; ++i) {
    int c = sub + 32*i;
    float o = (v[i]-mu)*rs*g[c] + bb[c];
    sF32o[row*260 + c] = o;
    sFho[row*264 + c] = bf16_rne(o);
  }
}

// ---------------- mega kernel: tokenizer + 4 layers + classifier ----------
__global__ __launch_bounds__(1024, 4) void mega_kernel(
    const float* __restrict__ x,
    const float* __restrict__ ep, const float* __restrict__ ef, const float* __restrict__ ed,
    const float* __restrict__ plw, const float* __restrict__ plb,
    const float* __restrict__ piw, const float* __restrict__ pib,
    const ushort_t* __restrict__ fw_h, const ushort_t* __restrict__ fw_l,
    const float* __restrict__ fb,
    const float* __restrict__ tng, const float* __restrict__ tnb,
    const ushort_t* __restrict__ ipw_h, const ushort_t* __restrict__ ipw_l,
    const float* __restrict__ cw, const float* __restrict__ cb,
    const ushort_t* __restrict__ xpw_h, const ushort_t* __restrict__ xpw_l,
    const float* __restrict__ dpw, const float* __restrict__ dpb,
    const float* __restrict__ alog, const float* __restrict__ dsk,
    const ushort_t* __restrict__ opw_h, const ushort_t* __restrict__ opw_l,
    const float* __restrict__ lng, const float* __restrict__ lnb,
    const float* __restrict__ w1, const float* __restrict__ b1,
    const float* __restrict__ w2, const float* __restrict__ b2,
    float* __restrict__ out) {
  extern __shared__ __align__(16) char sm[];
  float*    sF32 = (float*)(sm + OFF_A);       // [32][260]
  ushort_t* sFh  = (ushort_t*)(sm + OFF_B);    // [32][264] feat bf16
  float*    sT2  = (float*)(sm + OFF_B);       // [32][260] f32 scratch
  float*    sDbc = (float*)(sm + OFF_B);       // 4 x [32][64]
  float*    sHid = (float*)(sm + OFF_B);       // [128]
  ushort_t* sU   = (ushort_t*)(sm + OFF_C);    // [32][520] u_pre -> u -> y
  ushort_t* catH = (ushort_t*)(sm + OFF_C);    // [32][168] tokenizer
  ushort_t* sZb  = (ushort_t*)(sm + OFF_D);    // [32][520] silu(z) bf16

  const int tid  = threadIdx.x;
  const int b    = blockIdx.x;
  const int wave = tid >> 6, lane = tid & 63;
  const int lm   = lane & 15, lq = lane >> 4;

  // ================= tokenizer =================
  {
    int r = tid >> 5, cl = tid & 31;
    const float* xr = x + ((size_t)b*64 + r)*5;
    float x0 = xr[0], x1 = xr[1], x2 = xr[2], x3 = xr[3], x4 = xr[4];
    int proto = min(max((int)x0, 0), 255);
    int flags = min(max((int)x2, 0), 63);
    int direc = min(max((int)x4, 0), 1);
    #pragma unroll
    for (int j = 0; j < 6; ++j) {
      int c = cl + 32*j;
      if (c < 168) {
        float v;
        if (c < 32)       v = ep[proto*32 + c];
        else if (c < 64)  v = x1*plw[c-32] + plb[c-32];
        else if (c < 96)  v = ef[flags*32 + (c-64)];
        else if (c < 128) v = x3*piw[c-96] + pib[c-96];
        else if (c < 136) v = ed[direc*8 + (c-128)];
        else              v = 0.f;
        catH[r*168 + c] = bf16_rne(v);
      }
    }
  }
  __syncthreads();
  // fusion GEMM: pre = cat @ fw^T (M=32, N=256, K=160); 16 waves x 16 cols
  {
    f32x4 acc[2] = {(f32x4){0.f,0.f,0.f,0.f}, (f32x4){0.f,0.f,0.f,0.f}};
    int nb = wave*16;
    gemm1<5, 168, 160>(catH + lm*168 + lq*8,
                       fw_h + (size_t)(nb+lm)*160 + lq*8,
                       fw_l + (size_t)(nb+lm)*160 + lq*8, acc);
    #pragma unroll
    for (int mi = 0; mi < 2; ++mi)
      #pragma unroll
      for (int r2 = 0; r2 < 4; ++r2)
        sT2[(mi*16 + lq*4 + r2)*260 + nb + lm] = acc[mi][r2];
  }
  __syncthreads();
  ln_block(sT2, nullptr, fb, tng, tnb, sF32, sFh, tid);
  __syncthreads();

  // ================= 4 mamba layers =================
  #pragma unroll 1
  for (int l = 0; l < 4; ++l) {
    const ushort_t* iph = ipw_h + (size_t)l*1024*256;
    const ushort_t* ipl2= ipw_l + (size_t)l*1024*256;
    const ushort_t* xph = xpw_h + (size_t)l*64*512;
    const ushort_t* xpl = xpw_l + (size_t)l*64*512;
    const ushort_t* oph = opw_h + (size_t)l*256*512;
    const ushort_t* opl = opw_l + (size_t)l*256*512;
    const ushort_t* sA = sFh + lm*264 + lq*8;

    // ---- Z GEMM: 16 waves x 32 cols -> silu(z) bf16 into sZb (region D) ----
    {
      f32x4 acc[2][2];
      #pragma unroll
      for (int mi = 0; mi < 2; ++mi)
        #pragma unroll
        for (int nt = 0; nt < 2; ++nt) acc[mi][nt] = (f32x4){0.f,0.f,0.f,0.f};
      int row0 = 512 + wave*32;
      gemm2<8, 264, 256>(sA,
                         iph + (size_t)(row0+lm)*256 + lq*8,
                         ipl2 + (size_t)(row0+lm)*256 + lq*8, acc);
      int nb = wave*32;
      #pragma unroll
      for (int mi = 0; mi < 2; ++mi)
        #pragma unroll
        for (int nt = 0; nt < 2; ++nt)
          #pragma unroll
          for (int r2 = 0; r2 < 4; ++r2) {
            int t = mi*16 + lq*4 + r2;
            int n = nb + nt*16 + lm;
            sZb[t*520 + n] = bf16_rne(silu_f(acc[mi][nt][r2]));
          }
    }

    // ---- U GEMM: 16 waves x 32 cols -> u_pre bf16 into sU (region C) ----
    {
      f32x4 acc[2][2];
      #pragma unroll
      for (int mi = 0; mi < 2; ++mi)
        #pragma unroll
        for (int nt = 0; nt < 2; ++nt) acc[mi][nt] = (f32x4){0.f,0.f,0.f,0.f};
      int row0 = wave*32;
      gemm2<8, 264, 256>(sA,
                         iph + (size_t)(row0+lm)*256 + lq*8,
                         ipl2 + (size_t)(row0+lm)*256 + lq*8, acc);
      int nb = wave*32;
      #pragma unroll
      for (int mi = 0; mi < 2; ++mi)
        #pragma unroll
        for (int nt = 0; nt < 2; ++nt)
          #pragma unroll
          for (int r2 = 0; r2 < 4; ++r2) {
            int t = mi*16 + lq*4 + r2;
            int n = nb + nt*16 + lm;
            sU[t*520 + n] = bf16_rne(acc[mi][nt][r2]);
          }
    }
    __syncthreads();

    // ---- conv + silu: c = tid&511 channel, hv = tid>>9 t-half ----
    {
      int c = tid & 511, hv = tid >> 9;
      int h16 = hv*16;
      float xw[19];
      #pragma unroll
      for (int j = 0; j < 19; ++j) {
        int gt = h16 + j - 3;
        xw[j] = (gt >= 0) ? bf16_to_f(sU[gt*520 + c]) : 0.f;
      }
      __syncthreads();    // hv=1's t13..15 reads before hv=0 overwrites them
      const float* cwl = cw + (size_t)l*2048 + (size_t)c*4;
      float w0 = cwl[0], w1c = cwl[1], w2c = cwl[2], w3 = cwl[3];
      float bias = cb[l*512 + c];
      #pragma unroll
      for (int tt = 0; tt < 16; ++tt) {
        float a = bias + w0*xw[tt] + w1c*xw[tt+1] + w2c*xw[tt+2] + w3*xw[tt+3];
        sU[(h16+tt)*520 + c] = bf16_rne(silu_f(a));
      }
    }
    __syncthreads();

    // ---- xproj: 16 waves = 4 row-groups x 4 K-quarters -> sDbc partials ----
    // (sFh dead after Z/U; region B reused as sDbc)
    {
      int wg = wave & 3, kh = wave >> 2;
      f32x4 acx[2] = {(f32x4){0.f,0.f,0.f,0.f}, (f32x4){0.f,0.f,0.f,0.f}};
      gemm1<4, 520, 512>(sU + lm*520 + kh*128 + lq*8,
                         xph + (size_t)(wg*16+lm)*512 + kh*128 + lq*8,
                         xpl + (size_t)(wg*16+lm)*512 + kh*128 + lq*8, acx);
      float* dst = sDbc + kh*2048;
      #pragma unroll
      for (int mi = 0; mi < 2; ++mi)
        #pragma unroll
        for (int r2 = 0; r2 < 4; ++r2)
          dst[(mi*16 + lq*4 + r2)*64 + wg*16 + lm] = acx[mi][r2];
    }
    __syncthreads();
    {
      int i0 = tid*2;
      #pragma unroll
      for (int j = 0; j < 2; ++j) {
        int i = i0 + j;
        sDbc[i] += sDbc[2048+i] + sDbc[4096+i] + sDbc[6144+i];
      }
    }
    __syncthreads();

    // ---- dtproj + scan + gate: thread pair per channel, n split 8+8 ----
    // (vectorized f32x4 row reads; accumulation order identical to v19)
    {
      int c = tid >> 1, p = tid & 1;
      const float* dpwl = dpw + (size_t)l*8192 + (size_t)c*16 + p*8;
      float wv[8];
      #pragma unroll
      for (int j = 0; j < 8; ++j) wv[j] = dpwl[j];
      const float* al2 = alog + (size_t)l*8192 + (size_t)c*16 + p*8;
      float cc[8], hst[8];
      #pragma unroll
      for (int j = 0; j < 8; ++j) {
        cc[j] = -__expf(al2[j]) * 1.44269504f;
        hst[j] = 0.f;
      }
      float bias = dpb[l*512 + c], dskv = dsk[l*512 + c];
      #pragma unroll 2
      for (int t = 0; t < 32; ++t) {
        const float* rowp = sDbc + t*64 + p*8;
        f32x4 rd0 = *(const f32x4*)(rowp);
        f32x4 rd1 = *(const f32x4*)(rowp + 4);
        float raw = 0.f;
        #pragma unroll
        for (int j = 0; j < 4; ++j) raw += wv[j]*rd0[j];
        #pragma unroll
        for (int j = 0; j < 4; ++j) raw += wv[4+j]*rd1[j];
        raw += __shfl_xor(raw, 1);
        raw += bias;
        float dtv = (raw > 20.f) ? raw : __logf(1.f + __expf(raw));
        int ui = t*520 + c;
        float uv = bf16_to_f(sU[ui]);
        float du = dtv * uv;
        f32x4 rb0 = *(const f32x4*)(rowp + 16);
        f32x4 rb1 = *(const f32x4*)(rowp + 20);
        f32x4 rc0 = *(const f32x4*)(rowp + 32);
        f32x4 rc1 = *(const f32x4*)(rowp + 36);
        float yv = 0.f;
        #pragma unroll
        for (int j = 0; j < 4; ++j) {
          float en = exp2f(dtv * cc[j]);
          hst[j] = en*hst[j] + du*rb0[j];
          yv += hst[j]*rc0[j];
        }
        #pragma unroll
        for (int j = 0; j < 4; ++j) {
          float en = exp2f(dtv * cc[4+j]);
          hst[4+j] = en*hst[4+j] + du*rb1[j];
          yv += hst[4+j]*rc1[j];
        }
        yv += __shfl_xor(yv, 1);
        if (p == 0) {
          float g = (yv + uv*dskv) * bf16_to_f(sZb[ui]);
          sU[ui] = bf16_rne(g);
        }
      }
    }
    __syncthreads();

    // ---- out_proj (256 x 512): 16 waves x 16 cols ----
    {
      f32x4 ao[2] = {(f32x4){0.f,0.f,0.f,0.f}, (f32x4){0.f,0.f,0.f,0.f}};
      int nb = wave*16;
      gemm1<16, 520, 512>(sU + lm*520 + lq*8,
                          oph + (size_t)(nb+lm)*512 + lq*8,
                          opl + (size_t)(nb+lm)*512 + lq*8, ao);
      // sDbc dead (scan barrier passed); sT2 (B) writable
      #pragma unroll
      for (int mi = 0; mi < 2; ++mi)
        #pragma unroll
        for (int r2 = 0; r2 < 4; ++r2)
          sT2[(mi*16 + lq*4 + r2)*260 + nb + lm] = ao[mi][r2];
    }
    __syncthreads();
    ln_block(sT2, sF32, nullptr, lng, lnb, sF32, sFh, tid);
    __syncthreads();
  }

  // ================= classifier (token 31) =================
  {
    int o = tid >> 3, q = tid & 7;
    const float* fr = sF32 + 31*260 + q*32;
    const float* wr = w1 + (size_t)o*256 + q*32;
    float s = 0.f;
    #pragma unroll 8
    for (int k = 0; k < 32; ++k) s += wr[k]*fr[k];
    s += __shfl_xor(s, 1); s += __shfl_xor(s, 2); s += __shfl_xor(s, 4);
    if (q == 0) sHid[o] = fmaxf(s + b1[o], 0.f);
    __syncthreads();
    if (tid < 2) {
      float oo = b2[tid];
      #pragma unroll 8
      for (int k = 0; k < 128; ++k) oo += w2[tid*128 + k]*sHid[k];
      out[b*2 + tid] = oo;
    }
  }
}

// ---------------- launch ----------------
extern "C" void kernel_launch(void* const* d_in, const int* in_sizes, int n_in,
                              void* d_out, int out_size, void* d_ws, size_t ws_size,
                              hipStream_t stream) {
  const float* x    = (const float*)d_in[0];
  const float* ep   = (const float*)d_in[1];
  const float* ef   = (const float*)d_in[2];
  const float* ed   = (const float*)d_in[3];
  const float* plw  = (const float*)d_in[4];
  const float* plb  = (const float*)d_in[5];
  const float* piw  = (const float*)d_in[6];
  const float* pib  = (const float*)d_in[7];
  const float* fw   = (const float*)d_in[8];
  const float* fb   = (const float*)d_in[9];
  const float* tng  = (const float*)d_in[10];
  const float* tnb  = (const float*)d_in[11];
  const float* ipw  = (const float*)d_in[12];
  const float* cw   = (const float*)d_in[13];
  const float* cb   = (const float*)d_in[14];
  const float* xpw  = (const float*)d_in[15];
  const float* dpw  = (const float*)d_in[16];
  const float* dpb  = (const float*)d_in[17];
  const float* alog = (const float*)d_in[18];
  const float* dsk  = (const float*)d_in[19];
  const float* opw  = (const float*)d_in[20];
  const float* lng  = (const float*)d_in[21];
  const float* lnb  = (const float*)d_in[22];
  const float* w1   = (const float*)d_in[23];
  const float* b1   = (const float*)d_in[24];
  const float* w2   = (const float*)d_in[25];
  const float* b2   = (const float*)d_in[26];

  ushort_t* ipw_h = (ushort_t*)d_ws;
  ushort_t* ipw_l = ipw_h + (size_t)NIP;
  ushort_t* opw_h = ipw_l + (size_t)NIP;
  ushort_t* opw_l = opw_h + (size_t)NOP;
  ushort_t* xpw_h = opw_l + (size_t)NOP;
  ushort_t* xpw_l = xpw_h + (size_t)NXP;
  ushort_t* fw_h  = xpw_l + (size_t)NXP;
  ushort_t* fw_l  = fw_h  + (size_t)NFW;

  static int smem_set = 0;
  if (!smem_set) {
    hipFuncSetAttribute(reinterpret_cast<const void*>(mega_kernel),
                        hipFuncAttributeMaxDynamicSharedMemorySize, SMEM_TOTAL);
    smem_set = 1;
  }

  prep_w<<<NPREP/256, 256, 0, stream>>>(ipw, opw, xpw, fw,
      ipw_h, ipw_l, opw_h, opw_l, xpw_h, xpw_l, fw_h, fw_l);

  mega_kernel<<<BATCH, 1024, SMEM_TOTAL, stream>>>(
      x, ep, ef, ed, plw, plb, piw, pib,
      fw_h, fw_l, fb, tng, tnb,
      ipw_h, ipw_l, cw, cb, xpw_h, xpw_l,
      dpw, dpb, alog, dsk, opw_h, opw_l,
      lng, lnb, w1, b1, w2, b2, (float*)d_out);
}

// Round 21
// 350.584 us; speedup vs baseline: 2.9814x; 1.2642x over previous
//
#include <hip/hip_runtime.h>
#include <math.h>

// BlockwiseEarlyExitMamba: B=128, L=64, EXIT_POS=32 -> only t<32 matter.
// v23 = v22 (passing, 342us) with SINGLE-bf16 weights: drop the lo-correction
// stream (bf16_split's hi == RNE(w)). Halves per-block weight traffic
// (6.8 -> 3.4 MB, the dominant GEMM cost per the round-19 ablation: GEMM-added
// = 188us at 3.3% MfmaUtil = weight streaming) and halves MFMA count.
// Risk: weight rounding ~2^-9 doubles absmax to ~0.004 (threshold 0.00797).
#define BATCH 128

using bf16x8 = __attribute__((ext_vector_type(8))) short;
using f32x4  = __attribute__((ext_vector_type(4))) float;
typedef unsigned short ushort_t;
typedef unsigned int   uint_t;

__device__ __forceinline__ float silu_f(float x) { return x / (1.f + __expf(-x)); }

__device__ __forceinline__ ushort_t bf16_rne(float f) {
  unsigned int u = __float_as_uint(f);
  u += 0x7FFFu + ((u >> 16) & 1u);
  return (ushort_t)(u >> 16);
}
__device__ __forceinline__ float bf16_to_f(ushort_t h) {
  return __uint_as_float(((unsigned int)h) << 16);
}
__device__ __forceinline__ void bf16_split(float f, ushort_t& hi, ushort_t& lo) {
  hi = bf16_rne(f);
  lo = bf16_rne(f - bf16_to_f(hi));
}

// 2-tile (32 out cols) GEMM, single-bf16 weights, straight loop.
template<int KSTEPS, int AP, int WP>
__device__ __forceinline__ void gemm2(
    const ushort_t* sA, const ushort_t* wh, f32x4 acc[2][2]) {
  for (int ks = 0; ks < KSTEPS; ++ks) {
    int k0 = ks*32;
    bf16x8 a0 = *(const bf16x8*)(sA + k0);
    bf16x8 a1 = *(const bf16x8*)(sA + 16*AP + k0);
    bf16x8 w0 = *(const bf16x8*)(wh + k0);
    bf16x8 w1 = *(const bf16x8*)(wh + 16*WP + k0);
    acc[0][0] = __builtin_amdgcn_mfma_f32_16x16x32_bf16(a0, w0, acc[0][0], 0, 0, 0);
    acc[1][0] = __builtin_amdgcn_mfma_f32_16x16x32_bf16(a1, w0, acc[1][0], 0, 0, 0);
    acc[0][1] = __builtin_amdgcn_mfma_f32_16x16x32_bf16(a0, w1, acc[0][1], 0, 0, 0);
    acc[1][1] = __builtin_amdgcn_mfma_f32_16x16x32_bf16(a1, w1, acc[1][1], 0, 0, 0);
  }
}

// 1-tile (16 out cols) variant.
template<int KSTEPS, int AP, int WP>
__device__ __forceinline__ void gemm1(
    const ushort_t* sA, const ushort_t* wh, f32x4 acc[2]) {
  for (int ks = 0; ks < KSTEPS; ++ks) {
    int k0 = ks*32;
    bf16x8 a0 = *(const bf16x8*)(sA + k0);
    bf16x8 a1 = *(const bf16x8*)(sA + 16*AP + k0);
    bf16x8 w0 = *(const bf16x8*)(wh + k0);
    acc[0] = __builtin_amdgcn_mfma_f32_16x16x32_bf16(a0, w0, acc[0], 0, 0, 0);
    acc[1] = __builtin_amdgcn_mfma_f32_16x16x32_bf16(a1, w0, acc[1], 0, 0, 0);
  }
}

// ---------------- merged weight prep: fp32 -> hi/lo bf16 (lo unused now) ----
#define NIP (4*1024*256)
#define NOP (4*256*512)
#define NXP (4*64*512)
#define NFW (256*160)
#define NPREP (NIP+NOP+NXP+NFW)   // 1744896 = 6816*256
__global__ __launch_bounds__(256) void prep_w(
    const float* __restrict__ ipw, const float* __restrict__ opw,
    const float* __restrict__ xpw, const float* __restrict__ fw,
    ushort_t* __restrict__ ih, ushort_t* __restrict__ il,
    ushort_t* __restrict__ oh, ushort_t* __restrict__ ol,
    ushort_t* __restrict__ xh, ushort_t* __restrict__ xl,
    ushort_t* __restrict__ fh, ushort_t* __restrict__ fl) {
  int i = blockIdx.x*256 + threadIdx.x;
  float v; ushort_t h, l;
  if (i < NIP) {
    v = ipw[i]; bf16_split(v, h, l); ih[i] = h; il[i] = l;
  } else if (i < NIP+NOP) {
    int j = i - NIP;
    v = opw[j]; bf16_split(v, h, l); oh[j] = h; ol[j] = l;
  } else if (i < NIP+NOP+NXP) {
    int j = i - (NIP+NOP);
    int lay = j >> 15;
    int r = (j >> 9) & 63, c = j & 511;
    v = (r < 48) ? xpw[(size_t)lay*48*512 + r*512 + c] : 0.f;
    bf16_split(v, h, l); xh[j] = h; xl[j] = l;
  } else {
    int j = i - (NIP+NOP+NXP);
    int r = j / 160, c = j - r*160;
    v = (c < 136) ? fw[r*136 + c] : 0.f;
    bf16_split(v, h, l); fh[j] = h; fl[j] = l;
  }
}

// ---------------- LDS layout (bytes) ----------------
// A: sF32 f32 [32][260]             33280  (residual feat, persistent)
// B: union { sFh us [32][264] (feat bf16) | sT2 f32 [32][260] |
//            sDbc f32 4x[32][64] | sHid f32[128] }   33280
// C: sU  us [32][520]               33280  (u_pre -> u -> y; aliased catH)
// D: sZb us [32][520]               33280  (silu(z) bf16)
#define OFF_A 0
#define OFF_B 33280
#define OFF_C 66560
#define OFF_D 99840
#define SMEM_TOTAL 133120

// LN of [32][256]; 32 threads/row (1024 threads). Reads sIn (+resid +addv);
// internal barrier; writes sF32o + bf16 sFho.
__device__ __forceinline__ void ln_block(
    const float* sIn, const float* resid, const float* addv,
    const float* __restrict__ g, const float* __restrict__ bb,
    float* sF32o, ushort_t* sFho, int tid) {
  int row = tid >> 5, sub = tid & 31;
  float v[8];
  float s = 0.f;
  #pragma unroll
  for (int i = 0; i < 8; ++i) {
    int c = sub + 32*i;
    float t = sIn[row*260 + c];
    if (resid) t += resid[row*260 + c];
    if (addv)  t += addv[c];
    v[i] = t; s += t;
  }
  s += __shfl_xor(s, 1); s += __shfl_xor(s, 2); s += __shfl_xor(s, 4);
  s += __shfl_xor(s, 8); s += __shfl_xor(s, 16);
  float mu = s * (1.f/256.f);
  float s2 = 0.f;
  #pragma unroll
  for (int i = 0; i < 8; ++i) { float dv = v[i]-mu; s2 += dv*dv; }
  s2 += __shfl_xor(s2, 1); s2 += __shfl_xor(s2, 2); s2 += __shfl_xor(s2, 4);
  s2 += __shfl_xor(s2, 8); s2 += __shfl_xor(s2, 16);
  float rs = rsqrtf(s2*(1.f/256.f) + 1e-5f);
  __syncthreads();              // sIn aliases sFho: read-before, write-after
  #pragma unroll
  for (int i = 0; i < 8; ++i) {
    int c = sub + 32*i;
    float o = (v[i]-mu)*rs*g[c] + bb[c];
    sF32o[row*260 + c] = o;
    sFho[row*264 + c] = bf16_rne(o);
  }
}

// ---------------- mega kernel: tokenizer + 4 layers + classifier ----------
__global__ __launch_bounds__(1024, 4) void mega_kernel(
    const float* __restrict__ x,
    const float* __restrict__ ep, const float* __restrict__ ef, const float* __restrict__ ed,
    const float* __restrict__ plw, const float* __restrict__ plb,
    const float* __restrict__ piw, const float* __restrict__ pib,
    const ushort_t* __restrict__ fw_h,
    const float* __restrict__ fb,
    const float* __restrict__ tng, const float* __restrict__ tnb,
    const ushort_t* __restrict__ ipw_h,
    const float* __restrict__ cw, const float* __restrict__ cb,
    const ushort_t* __restrict__ xpw_h,
    const float* __restrict__ dpw, const float* __restrict__ dpb,
    const float* __restrict__ alog, const float* __restrict__ dsk,
    const ushort_t* __restrict__ opw_h,
    const float* __restrict__ lng, const float* __restrict__ lnb,
    const float* __restrict__ w1, const float* __restrict__ b1,
    const float* __restrict__ w2, const float* __restrict__ b2,
    float* __restrict__ out) {
  extern __shared__ __align__(16) char sm[];
  float*    sF32 = (float*)(sm + OFF_A);       // [32][260]
  ushort_t* sFh  = (ushort_t*)(sm + OFF_B);    // [32][264] feat bf16
  float*    sT2  = (float*)(sm + OFF_B);       // [32][260] f32 scratch
  float*    sDbc = (float*)(sm + OFF_B);       // 4 x [32][64]
  float*    sHid = (float*)(sm + OFF_B);       // [128]
  ushort_t* sU   = (ushort_t*)(sm + OFF_C);    // [32][520] u_pre -> u -> y
  ushort_t* catH = (ushort_t*)(sm + OFF_C);    // [32][168] tokenizer
  ushort_t* sZb  = (ushort_t*)(sm + OFF_D);    // [32][520] silu(z) bf16

  const int tid  = threadIdx.x;
  const int b    = blockIdx.x;
  const int wave = tid >> 6, lane = tid & 63;
  const int lm   = lane & 15, lq = lane >> 4;

  // ================= tokenizer =================
  {
    int r = tid >> 5, cl = tid & 31;
    const float* xr = x + ((size_t)b*64 + r)*5;
    float x0 = xr[0], x1 = xr[1], x2 = xr[2], x3 = xr[3], x4 = xr[4];
    int proto = min(max((int)x0, 0), 255);
    int flags = min(max((int)x2, 0), 63);
    int direc = min(max((int)x4, 0), 1);
    #pragma unroll
    for (int j = 0; j < 6; ++j) {
      int c = cl + 32*j;
      if (c < 168) {
        float v;
        if (c < 32)       v = ep[proto*32 + c];
        else if (c < 64)  v = x1*plw[c-32] + plb[c-32];
        else if (c < 96)  v = ef[flags*32 + (c-64)];
        else if (c < 128) v = x3*piw[c-96] + pib[c-96];
        else if (c < 136) v = ed[direc*8 + (c-128)];
        else              v = 0.f;
        catH[r*168 + c] = bf16_rne(v);
      }
    }
  }
  __syncthreads();
  // fusion GEMM: pre = cat @ fw^T (M=32, N=256, K=160); 16 waves x 16 cols
  {
    f32x4 acc[2] = {(f32x4){0.f,0.f,0.f,0.f}, (f32x4){0.f,0.f,0.f,0.f}};
    int nb = wave*16;
    gemm1<5, 168, 160>(catH + lm*168 + lq*8,
                       fw_h + (size_t)(nb+lm)*160 + lq*8, acc);
    #pragma unroll
    for (int mi = 0; mi < 2; ++mi)
      #pragma unroll
      for (int r2 = 0; r2 < 4; ++r2)
        sT2[(mi*16 + lq*4 + r2)*260 + nb + lm] = acc[mi][r2];
  }
  __syncthreads();
  ln_block(sT2, nullptr, fb, tng, tnb, sF32, sFh, tid);
  __syncthreads();

  // ================= 4 mamba layers =================
  #pragma unroll 1
  for (int l = 0; l < 4; ++l) {
    const ushort_t* iph = ipw_h + (size_t)l*1024*256;
    const ushort_t* xph = xpw_h + (size_t)l*64*512;
    const ushort_t* oph = opw_h + (size_t)l*256*512;
    const ushort_t* sA = sFh + lm*264 + lq*8;

    // ---- Z GEMM: 16 waves x 32 cols -> silu(z) bf16 into sZb (region D) ----
    {
      f32x4 acc[2][2];
      #pragma unroll
      for (int mi = 0; mi < 2; ++mi)
        #pragma unroll
        for (int nt = 0; nt < 2; ++nt) acc[mi][nt] = (f32x4){0.f,0.f,0.f,0.f};
      int row0 = 512 + wave*32;
      gemm2<8, 264, 256>(sA, iph + (size_t)(row0+lm)*256 + lq*8, acc);
      int nb = wave*32;
      #pragma unroll
      for (int mi = 0; mi < 2; ++mi)
        #pragma unroll
        for (int nt = 0; nt < 2; ++nt)
          #pragma unroll
          for (int r2 = 0; r2 < 4; ++r2) {
            int t = mi*16 + lq*4 + r2;
            int n = nb + nt*16 + lm;
            sZb[t*520 + n] = bf16_rne(silu_f(acc[mi][nt][r2]));
          }
    }

    // ---- U GEMM: 16 waves x 32 cols -> u_pre bf16 into sU (region C) ----
    {
      f32x4 acc[2][2];
      #pragma unroll
      for (int mi = 0; mi < 2; ++mi)
        #pragma unroll
        for (int nt = 0; nt < 2; ++nt) acc[mi][nt] = (f32x4){0.f,0.f,0.f,0.f};
      int row0 = wave*32;
      gemm2<8, 264, 256>(sA, iph + (size_t)(row0+lm)*256 + lq*8, acc);
      int nb = wave*32;
      #pragma unroll
      for (int mi = 0; mi < 2; ++mi)
        #pragma unroll
        for (int nt = 0; nt < 2; ++nt)
          #pragma unroll
          for (int r2 = 0; r2 < 4; ++r2) {
            int t = mi*16 + lq*4 + r2;
            int n = nb + nt*16 + lm;
            sU[t*520 + n] = bf16_rne(acc[mi][nt][r2]);
          }
    }
    __syncthreads();

    // ---- conv + silu: c = tid&511 channel, hv = tid>>9 t-half ----
    {
      int c = tid & 511, hv = tid >> 9;
      int h16 = hv*16;
      float xw[19];
      #pragma unroll
      for (int j = 0; j < 19; ++j) {
        int gt = h16 + j - 3;
        xw[j] = (gt >= 0) ? bf16_to_f(sU[gt*520 + c]) : 0.f;
      }
      __syncthreads();    // hv=1's t13..15 reads before hv=0 overwrites them
      const float* cwl = cw + (size_t)l*2048 + (size_t)c*4;
      float w0 = cwl[0], w1c = cwl[1], w2c = cwl[2], w3 = cwl[3];
      float bias = cb[l*512 + c];
      #pragma unroll
      for (int tt = 0; tt < 16; ++tt) {
        float a = bias + w0*xw[tt] + w1c*xw[tt+1] + w2c*xw[tt+2] + w3*xw[tt+3];
        sU[(h16+tt)*520 + c] = bf16_rne(silu_f(a));
      }
    }
    __syncthreads();

    // ---- xproj: 16 waves = 4 row-groups x 4 K-quarters -> sDbc partials ----
    // (sFh dead after Z/U; region B reused as sDbc)
    {
      int wg = wave & 3, kh = wave >> 2;
      f32x4 acx[2] = {(f32x4){0.f,0.f,0.f,0.f}, (f32x4){0.f,0.f,0.f,0.f}};
      gemm1<4, 520, 512>(sU + lm*520 + kh*128 + lq*8,
                         xph + (size_t)(wg*16+lm)*512 + kh*128 + lq*8, acx);
      float* dst = sDbc + kh*2048;
      #pragma unroll
      for (int mi = 0; mi < 2; ++mi)
        #pragma unroll
        for (int r2 = 0; r2 < 4; ++r2)
          dst[(mi*16 + lq*4 + r2)*64 + wg*16 + lm] = acx[mi][r2];
    }
    __syncthreads();
    {
      int i0 = tid*2;
      #pragma unroll
      for (int j = 0; j < 2; ++j) {
        int i = i0 + j;
        sDbc[i] += sDbc[2048+i] + sDbc[4096+i] + sDbc[6144+i];
      }
    }
    __syncthreads();

    // ---- dtproj + scan + gate: thread pair per channel, n split 8+8 ----
    {
      int c = tid >> 1, p = tid & 1;
      const float* dpwl = dpw + (size_t)l*8192 + (size_t)c*16 + p*8;
      float wv[8];
      #pragma unroll
      for (int j = 0; j < 8; ++j) wv[j] = dpwl[j];
      const float* al2 = alog + (size_t)l*8192 + (size_t)c*16 + p*8;
      float cc[8], hst[8];
      #pragma unroll
      for (int j = 0; j < 8; ++j) {
        cc[j] = -__expf(al2[j]) * 1.44269504f;
        hst[j] = 0.f;
      }
      float bias = dpb[l*512 + c], dskv = dsk[l*512 + c];
      #pragma unroll 2
      for (int t = 0; t < 32; ++t) {
        const float* rowp = sDbc + t*64 + p*8;
        f32x4 rd0 = *(const f32x4*)(rowp);
        f32x4 rd1 = *(const f32x4*)(rowp + 4);
        float raw = 0.f;
        #pragma unroll
        for (int j = 0; j < 4; ++j) raw += wv[j]*rd0[j];
        #pragma unroll
        for (int j = 0; j < 4; ++j) raw += wv[4+j]*rd1[j];
        raw += __shfl_xor(raw, 1);
        raw += bias;
        float dtv = (raw > 20.f) ? raw : __logf(1.f + __expf(raw));
        int ui = t*520 + c;
        float uv = bf16_to_f(sU[ui]);
        float du = dtv * uv;
        f32x4 rb0 = *(const f32x4*)(rowp + 16);
        f32x4 rb1 = *(const f32x4*)(rowp + 20);
        f32x4 rc0 = *(const f32x4*)(rowp + 32);
        f32x4 rc1 = *(const f32x4*)(rowp + 36);
        float yv = 0.f;
        #pragma unroll
        for (int j = 0; j < 4; ++j) {
          float en = exp2f(dtv * cc[j]);
          hst[j] = en*hst[j] + du*rb0[j];
          yv += hst[j]*rc0[j];
        }
        #pragma unroll
        for (int j = 0; j < 4; ++j) {
          float en = exp2f(dtv * cc[4+j]);
          hst[4+j] = en*hst[4+j] + du*rb1[j];
          yv += hst[4+j]*rc1[j];
        }
        yv += __shfl_xor(yv, 1);
        if (p == 0) {
          float g = (yv + uv*dskv) * bf16_to_f(sZb[ui]);
          sU[ui] = bf16_rne(g);
        }
      }
    }
    __syncthreads();

    // ---- out_proj (256 x 512): 16 waves x 16 cols ----
    {
      f32x4 ao[2] = {(f32x4){0.f,0.f,0.f,0.f}, (f32x4){0.f,0.f,0.f,0.f}};
      int nb = wave*16;
      gemm1<16, 520, 512>(sU + lm*520 + lq*8,
                          oph + (size_t)(nb+lm)*512 + lq*8, ao);
      // sDbc dead (scan barrier passed); sT2 (B) writable
      #pragma unroll
      for (int mi = 0; mi < 2; ++mi)
        #pragma unroll
        for (int r2 = 0; r2 < 4; ++r2)
          sT2[(mi*16 + lq*4 + r2)*260 + nb + lm] = ao[mi][r2];
    }
    __syncthreads();
    ln_block(sT2, sF32, nullptr, lng, lnb, sF32, sFh, tid);
    __syncthreads();
  }

  // ================= classifier (token 31) =================
  {
    int o = tid >> 3, q = tid & 7;
    const float* fr = sF32 + 31*260 + q*32;
    const float* wr = w1 + (size_t)o*256 + q*32;
    float s = 0.f;
    #pragma unroll 8
    for (int k = 0; k < 32; ++k) s += wr[k]*fr[k];
    s += __shfl_xor(s, 1); s += __shfl_xor(s, 2); s += __shfl_xor(s, 4);
    if (q == 0) sHid[o] = fmaxf(s + b1[o], 0.f);
    __syncthreads();
    if (tid < 2) {
      float oo = b2[tid];
      #pragma unroll 8
      for (int k = 0; k < 128; ++k) oo += w2[tid*128 + k]*sHid[k];
      out[b*2 + tid] = oo;
    }
  }
}

// ---------------- launch ----------------
extern "C" void kernel_launch(void* const* d_in, const int* in_sizes, int n_in,
                              void* d_out, int out_size, void* d_ws, size_t ws_size,
                              hipStream_t stream) {
  const float* x    = (const float*)d_in[0];
  const float* ep   = (const float*)d_in[1];
  const float* ef   = (const float*)d_in[2];
  const float* ed   = (const float*)d_in[3];
  const float* plw  = (const float*)d_in[4];
  const float* plb  = (const float*)d_in[5];
  const float* piw  = (const float*)d_in[6];
  const float* pib  = (const float*)d_in[7];
  const float* fw   = (const float*)d_in[8];
  const float* fb   = (const float*)d_in[9];
  const float* tng  = (const float*)d_in[10];
  const float* tnb  = (const float*)d_in[11];
  const float* ipw  = (const float*)d_in[12];
  const float* cw   = (const float*)d_in[13];
  const float* cb   = (const float*)d_in[14];
  const float* xpw  = (const float*)d_in[15];
  const float* dpw  = (const float*)d_in[16];
  const float* dpb  = (const float*)d_in[17];
  const float* alog = (const float*)d_in[18];
  const float* dsk  = (const float*)d_in[19];
  const float* opw  = (const float*)d_in[20];
  const float* lng  = (const float*)d_in[21];
  const float* lnb  = (const float*)d_in[22];
  const float* w1   = (const float*)d_in[23];
  const float* b1   = (const float*)d_in[24];
  const float* w2   = (const float*)d_in[25];
  const float* b2   = (const float*)d_in[26];

  ushort_t* ipw_h = (ushort_t*)d_ws;
  ushort_t* ipw_l = ipw_h + (size_t)NIP;
  ushort_t* opw_h = ipw_l + (size_t)NIP;
  ushort_t* opw_l = opw_h + (size_t)NOP;
  ushort_t* xpw_h = opw_l + (size_t)NOP;
  ushort_t* xpw_l = xpw_h + (size_t)NXP;
  ushort_t* fw_h  = xpw_l + (size_t)NXP;
  ushort_t* fw_l  = fw_h  + (size_t)NFW;

  static int smem_set = 0;
  if (!smem_set) {
    hipFuncSetAttribute(reinterpret_cast<const void*>(mega_kernel),
                        hipFuncAttributeMaxDynamicSharedMemorySize, SMEM_TOTAL);
    smem_set = 1;
  }

  prep_w<<<NPREP/256, 256, 0, stream>>>(ipw, opw, xpw, fw,
      ipw_h, ipw_l, opw_h, opw_l, xpw_h, xpw_l, fw_h, fw_l);

  mega_kernel<<<BATCH, 1024, SMEM_TOTAL, stream>>>(
      x, ep, ef, ed, plw, plb, piw, pib,
      fw_h, fb, tng, tnb,
      ipw_h, cw, cb, xpw_h,
      dpw, dpb, alog, dsk, opw_h,
      lng, lnb, w1, b1, w2, b2, (float*)d_out);
}